// Round 1
// 1135.373 us; speedup vs baseline: 1.1748x; 1.1748x over previous
//
#include <hip/hip_runtime.h>

// LSTM_26912265077001: 2-layer LSTM (H=51, IN=1), T=512, B=1024, fp32.
//
// V2 strategy: 3-role software-pipelined persistent kernel.
//   - 256 blocks (1/CU), 768 threads (12 waves/CU), NB=4 batch elems/block.
//   - Each matvec thread owns exactly ONE 52-float weight row in VGPRs
//     (previous version held 156 floats/thread -> AGPR/scratch shuffling,
//      VGPR_Count=104 proved weights were not in the vector file).
//   - Layer 2 runs one timestep behind layer 1, W_hh2*h2 and the output
//     dot run fully parallel with layer 1 -> only 2 barriers/timestep.
//
// Pipeline at iteration it (it = 0..T inclusive):
//   phase 1: R1  : gates1(it)      = b1 + W_ih1*x[it] + W_hh1*h1[it-1]
//            R2  : g2a(it-1)       = b2 + W_ih2*h1[it-1]
//            R3  : g2b(it-1)       = W_hh2*h2[it-2]
//            OUT : out[it-2]       = W_lin*h2[it-2] + b_lin
//   barrier
//   phase 2: E1 (=R1 threads): c1/h1[it] update
//            E2 (=R2 threads): c2/h2[it-1] update (g2a+g2b)
//   barrier

#define Hs   51
#define HP   52          // padded hidden (52 % 4 == 0, pad element is 0)
#define G4   204         // 4*H gate rows
#define Ts   512
#define Bs   1024
#define NB   4           // batch elements per block
#define NT   768         // threads per block (12 waves)

__device__ __forceinline__ float sig_(float x) {
    return 1.0f / (1.0f + __expf(-x));
}
__device__ __forceinline__ float tanh_(float x) {
    float e = __expf(2.0f * x);
    return 1.0f - 2.0f / (e + 1.0f);
}

// 4-batch matvec accumulate: A_b += w[:] . h[b][:]   (w is the named local
// register array in scope; macro avoids taking its address so SROA cannot
// bail out and demote it).
#define MATVEC4(HBASE, A0, A1, A2, A3)                                        \
    {                                                                         \
        const float4* p0_ = (const float4*)((HBASE));                         \
        const float4* p1_ = (const float4*)((HBASE) + HP);                    \
        const float4* p2_ = (const float4*)((HBASE) + 2 * HP);                \
        const float4* p3_ = (const float4*)((HBASE) + 3 * HP);                \
        _Pragma("unroll")                                                     \
        for (int k_ = 0; k_ < HP / 4; ++k_) {                                 \
            float4 v0_ = p0_[k_], v1_ = p1_[k_], v2_ = p2_[k_], v3_ = p3_[k_];\
            float w0_ = w[4 * k_ + 0], w1_ = w[4 * k_ + 1];                   \
            float w2_ = w[4 * k_ + 2], w3_ = w[4 * k_ + 3];                   \
            A0 = fmaf(w0_, v0_.x, A0); A0 = fmaf(w1_, v0_.y, A0);             \
            A0 = fmaf(w2_, v0_.z, A0); A0 = fmaf(w3_, v0_.w, A0);             \
            A1 = fmaf(w0_, v1_.x, A1); A1 = fmaf(w1_, v1_.y, A1);             \
            A1 = fmaf(w2_, v1_.z, A1); A1 = fmaf(w3_, v1_.w, A1);             \
            A2 = fmaf(w0_, v2_.x, A2); A2 = fmaf(w1_, v2_.y, A2);             \
            A2 = fmaf(w2_, v2_.z, A2); A2 = fmaf(w3_, v2_.w, A2);             \
            A3 = fmaf(w0_, v3_.x, A3); A3 = fmaf(w1_, v3_.y, A3);             \
            A3 = fmaf(w2_, v3_.z, A3); A3 = fmaf(w3_, v3_.w, A3);             \
        }                                                                     \
    }

__global__ __launch_bounds__(NT, 3) void lstm2_kernel(
    const float* __restrict__ x,      // (T, B, 1)
    const float* __restrict__ W_ih1,  // (204, 1)
    const float* __restrict__ W_hh1,  // (204, 51)
    const float* __restrict__ b_ih1,  // (204,)
    const float* __restrict__ b_hh1,  // (204,)
    const float* __restrict__ W_ih2,  // (204, 51)
    const float* __restrict__ W_hh2,  // (204, 51)
    const float* __restrict__ b_ih2,  // (204,)
    const float* __restrict__ b_hh2,  // (204,)
    const float* __restrict__ W_lin,  // (1, 51)
    const float* __restrict__ b_lin,  // (1,)
    float* __restrict__ out)          // (B, T)
{
    __shared__ __align__(16) float xs[Ts][NB];        // input slice
    __shared__ __align__(16) float h1b[2][NB][HP];    // h1 double buffer
    __shared__ __align__(16) float h2b[2][NB][HP];    // h2 double buffer
    __shared__ __align__(16) float g1[NB][G4];        // layer-1 gates
    __shared__ __align__(16) float g2a[NB][G4];       // layer-2 partial (W_ih2*h1)
    __shared__ __align__(16) float g2b[NB][G4];       // layer-2 partial (W_hh2*h2)
    __shared__ __align__(16) float wlin_s[HP];
    __shared__ float blin_s;

    const int tid = threadIdx.x;
    const int bg0 = blockIdx.x * NB;

    // ---- one-time preload: x slice into LDS ----
    for (int idx = tid; idx < Ts * NB; idx += NT) {
        int tt = idx >> 2;            // idx / NB
        int b  = idx & 3;             // idx % NB
        xs[tt][b] = x[tt * Bs + bg0 + b];
    }
    if (tid < 2 * NB * HP) {          // zero both parities of both h buffers
        ((float*)h1b)[tid] = 0.f;
        ((float*)h2b)[tid] = 0.f;
    }
    if (tid < HP) wlin_s[tid] = (tid < Hs) ? W_lin[tid] : 0.f;
    if (tid == 0) blin_s = b_lin[0];

    // ---- one-time preload: ONE weight row per thread into registers ----
    float w[HP];
    float bsum = 0.f, wih1 = 0.f;
    if (tid < G4) {                               // R1: W_hh1 row
        const float* src = W_hh1 + tid * Hs;
        #pragma unroll
        for (int k = 0; k < Hs; ++k) w[k] = src[k];
        w[Hs] = 0.f;
        bsum = b_ih1[tid] + b_hh1[tid];
        wih1 = W_ih1[tid];
    } else if (tid >= 256 && tid < 256 + G4) {    // R2: W_ih2 row
        const int r = tid - 256;
        const float* src = W_ih2 + r * Hs;
        #pragma unroll
        for (int k = 0; k < Hs; ++k) w[k] = src[k];
        w[Hs] = 0.f;
        bsum = b_ih2[r] + b_hh2[r];
    } else if (tid >= 512 && tid < 512 + G4) {    // R3: W_hh2 row
        const int r = tid - 512;
        const float* src = W_hh2 + r * Hs;
        #pragma unroll
        for (int k = 0; k < Hs; ++k) w[k] = src[k];
        w[Hs] = 0.f;
    }

    // elementwise-updater (b, j) mapping for E1 (R1 threads) / E2 (R2 threads)
    int eb = 0, ej = 0;
    if (tid < G4) { eb = tid / Hs; ej = tid - eb * Hs; }
    else if (tid >= 256 && tid < 256 + G4) {
        const int r = tid - 256; eb = r / Hs; ej = r - eb * Hs;
    }

    float cc = 0.f;   // c1 for E1 threads, c2 for E2 threads
    __syncthreads();

    for (int it = 0; it <= Ts; ++it) {
        // ================= phase 1 =================
        if (tid < G4) {
            if (it < Ts) {            // layer-1 gates for timestep it
                const int pr = (it - 1) & 1;      // h1[it-1]
                const float4 xv = *(const float4*)xs[it];
                float a0 = fmaf(wih1, xv.x, bsum);
                float a1 = fmaf(wih1, xv.y, bsum);
                float a2 = fmaf(wih1, xv.z, bsum);
                float a3 = fmaf(wih1, xv.w, bsum);
                MATVEC4(&h1b[pr][0][0], a0, a1, a2, a3);
                g1[0][tid] = a0; g1[1][tid] = a1;
                g1[2][tid] = a2; g1[3][tid] = a3;
            }
        } else if (tid < G4 + NB) {
            if (it >= 2) {            // output for timestep it-2
                const int b = tid - G4;
                const float4* hb = (const float4*)h2b[it & 1][b];
                const float4* wv = (const float4*)wlin_s;
                float s = blin_s;
                #pragma unroll
                for (int k = 0; k < HP / 4; ++k) {
                    float4 a = hb[k], ww = wv[k];
                    s += a.x * ww.x + a.y * ww.y + a.z * ww.z + a.w * ww.w;
                }
                out[(bg0 + b) * Ts + (it - 2)] = s;
            }
        } else if (tid >= 256 && tid < 256 + G4) {
            if (it >= 1) {            // W_ih2 * h1[it-1]  (layer-2, step it-1)
                const int r  = tid - 256;
                const int pr = (it - 1) & 1;
                float a0 = bsum, a1 = bsum, a2 = bsum, a3 = bsum;
                MATVEC4(&h1b[pr][0][0], a0, a1, a2, a3);
                g2a[0][r] = a0; g2a[1][r] = a1;
                g2a[2][r] = a2; g2a[3][r] = a3;
            }
        } else if (tid >= 512 && tid < 512 + G4) {
            if (it >= 1) {            // W_hh2 * h2[it-2]  (layer-2, step it-1)
                const int r  = tid - 512;
                const int pr = it & 1;            // (it-2) & 1 == it & 1
                float a0 = 0.f, a1 = 0.f, a2 = 0.f, a3 = 0.f;
                MATVEC4(&h2b[pr][0][0], a0, a1, a2, a3);
                g2b[0][r] = a0; g2b[1][r] = a1;
                g2b[2][r] = a2; g2b[3][r] = a3;
            }
        }
        __syncthreads();

        // ================= phase 2 =================
        if (tid < G4) {
            if (it < Ts) {            // E1: h1[it], c1
                float iv = sig_ (g1[eb][ej]);
                float fv = sig_ (g1[eb][Hs + ej]);
                float gv = tanh_(g1[eb][2 * Hs + ej]);
                float ov = sig_ (g1[eb][3 * Hs + ej]);
                cc = fmaf(fv, cc, iv * gv);
                h1b[it & 1][eb][ej] = ov * tanh_(cc);
            }
        } else if (tid >= 256 && tid < 256 + G4) {
            if (it >= 1) {            // E2: h2[it-1], c2
                float s0 = g2a[eb][ej]          + g2b[eb][ej];
                float s1 = g2a[eb][Hs + ej]     + g2b[eb][Hs + ej];
                float s2 = g2a[eb][2 * Hs + ej] + g2b[eb][2 * Hs + ej];
                float s3 = g2a[eb][3 * Hs + ej] + g2b[eb][3 * Hs + ej];
                float iv = sig_(s0);
                float fv = sig_(s1);
                float gv = tanh_(s2);
                float ov = sig_(s3);
                cc = fmaf(fv, cc, iv * gv);
                h2b[(it - 1) & 1][eb][ej] = ov * tanh_(cc);
            }
        }
        __syncthreads();
    }

    // ---- final output for t = T-1 (h2[T-1] produced at it = Ts) ----
    if (tid >= G4 && tid < G4 + NB) {
        const int b = tid - G4;
        const float4* hb = (const float4*)h2b[(Ts - 1) & 1][b];
        const float4* wv = (const float4*)wlin_s;
        float s = blin_s;
        #pragma unroll
        for (int k = 0; k < HP / 4; ++k) {
            float4 a = hb[k], ww = wv[k];
            s += a.x * ww.x + a.y * ww.y + a.z * ww.z + a.w * ww.w;
        }
        out[(bg0 + b) * Ts + (Ts - 1)] = s;
    }
}

extern "C" void kernel_launch(void* const* d_in, const int* in_sizes, int n_in,
                              void* d_out, int out_size, void* d_ws, size_t ws_size,
                              hipStream_t stream) {
    const float* x     = (const float*)d_in[0];
    const float* W_ih1 = (const float*)d_in[1];
    const float* W_hh1 = (const float*)d_in[2];
    const float* b_ih1 = (const float*)d_in[3];
    const float* b_hh1 = (const float*)d_in[4];
    const float* W_ih2 = (const float*)d_in[5];
    const float* W_hh2 = (const float*)d_in[6];
    const float* b_ih2 = (const float*)d_in[7];
    const float* b_hh2 = (const float*)d_in[8];
    const float* W_lin = (const float*)d_in[9];
    const float* b_lin = (const float*)d_in[10];
    float* out = (float*)d_out;

    lstm2_kernel<<<Bs / NB, NT, 0, stream>>>(
        x, W_ih1, W_hh1, b_ih1, b_hh1,
        W_ih2, W_hh2, b_ih2, b_hh2, W_lin, b_lin, out);
}